// Round 1
// baseline (3882.123 us; speedup 1.0000x reference)
//
#include <hip/hip_runtime.h>
#include <hip/hip_bf16.h>

#define NB 64      // batch
#define NS 40      // src len
#define NT 39      // tgt steps (T-1)
#define NE 256     // emb
#define NU 1024    // hidden
#define G3 3072    // 3*U
#define NVO 8192

// ---------------------------------------------------------------------------
// Generic 64x64 tile, 4x4 per-thread fp32 GEMM pieces
// ---------------------------------------------------------------------------

// GX = gather(emb, idx) @ W(256 x 3072) + bias ; rows = NB*cols_used
__global__ __launch_bounds__(256) void k_gx(const int* __restrict__ idx,
                                            int cols_total, int cols_used,
                                            const float* __restrict__ emb,
                                            const float* __restrict__ W,
                                            const float* __restrict__ bias,
                                            float* __restrict__ out)
{
    __shared__ float As[16][64];
    __shared__ float Bs[16][64];
    __shared__ int tok_sh[64];
    int tx = threadIdx.x;
    int row0 = blockIdx.x * 64;
    int col0 = blockIdx.y * 64;
    if (tx < 64) {
        int row = row0 + tx;
        int b = row / cols_used;
        int c = row - b * cols_used;
        tok_sh[tx] = idx[b * cols_total + c];
    }
    __syncthreads();
    int m_st = tx >> 2;            // 0..63
    int k_st = (tx & 3) * 4;       // 0,4,8,12
    int kb_st = tx >> 4;           // 0..15
    int nb_st = (tx & 15) * 4;
    int tn4 = (tx & 15) * 4;
    int tm4 = (tx >> 4) * 4;
    int tok = tok_sh[m_st];
    const float* Ab = emb + tok * NE + k_st;
    const float* Wb = W + kb_st * G3 + col0 + nb_st;
    float acc[4][4] = {};
    for (int kk = 0; kk < 16; ++kk) {
        float4 av = *(const float4*)(Ab + kk * 16);
        float4 bv = *(const float4*)(Wb + (size_t)kk * 16 * G3);
        __syncthreads();
        As[k_st + 0][m_st] = av.x;
        As[k_st + 1][m_st] = av.y;
        As[k_st + 2][m_st] = av.z;
        As[k_st + 3][m_st] = av.w;
        *(float4*)&Bs[kb_st][nb_st] = bv;
        __syncthreads();
#pragma unroll
        for (int k = 0; k < 16; ++k) {
            float4 a4 = *(const float4*)&As[k][tm4];
            float4 b4 = *(const float4*)&Bs[k][tn4];
            acc[0][0] += a4.x * b4.x; acc[0][1] += a4.x * b4.y; acc[0][2] += a4.x * b4.z; acc[0][3] += a4.x * b4.w;
            acc[1][0] += a4.y * b4.x; acc[1][1] += a4.y * b4.y; acc[1][2] += a4.y * b4.z; acc[1][3] += a4.y * b4.w;
            acc[2][0] += a4.z * b4.x; acc[2][1] += a4.z * b4.y; acc[2][2] += a4.z * b4.z; acc[2][3] += a4.z * b4.w;
            acc[3][0] += a4.w * b4.x; acc[3][1] += a4.w * b4.y; acc[3][2] += a4.w * b4.z; acc[3][3] += a4.w * b4.w;
        }
    }
    float4 bi = *(const float4*)(bias + col0 + tn4);
#pragma unroll
    for (int i = 0; i < 4; ++i) {
        float4 v = make_float4(acc[i][0] + bi.x, acc[i][1] + bi.y,
                               acc[i][2] + bi.z, acc[i][3] + bi.w);
        *(float4*)&out[(size_t)(row0 + tm4 + i) * G3 + col0 + tn4] = v;
    }
}

// Partial gh: P[kc][b][j] = sum_{k in chunk kc} A[b][k] * W[k][j]
// grid (48 col-tiles, 8 k-chunks of 128)
__global__ __launch_bounds__(256) void k_part(const float* __restrict__ A, int lda,
                                              const float* __restrict__ W,
                                              float* __restrict__ P)
{
    __shared__ float As[16][64];
    __shared__ float Bs[16][64];
    int tx = threadIdx.x;
    int col0 = blockIdx.x * 64;
    int kc = blockIdx.y;
    int m_st = tx >> 2;
    int k_st = (tx & 3) * 4;
    int kb_st = tx >> 4;
    int nb_st = (tx & 15) * 4;
    int tn4 = (tx & 15) * 4;
    int tm4 = (tx >> 4) * 4;
    const float* Ab = A + (size_t)m_st * lda + kc * 128 + k_st;
    const float* Wb = W + (size_t)(kc * 128 + kb_st) * G3 + col0 + nb_st;
    float acc[4][4] = {};
    for (int kk = 0; kk < 8; ++kk) {
        float4 av = *(const float4*)(Ab + kk * 16);
        float4 bv = *(const float4*)(Wb + (size_t)kk * 16 * G3);
        __syncthreads();
        As[k_st + 0][m_st] = av.x;
        As[k_st + 1][m_st] = av.y;
        As[k_st + 2][m_st] = av.z;
        As[k_st + 3][m_st] = av.w;
        *(float4*)&Bs[kb_st][nb_st] = bv;
        __syncthreads();
#pragma unroll
        for (int k = 0; k < 16; ++k) {
            float4 a4 = *(const float4*)&As[k][tm4];
            float4 b4 = *(const float4*)&Bs[k][tn4];
            acc[0][0] += a4.x * b4.x; acc[0][1] += a4.x * b4.y; acc[0][2] += a4.x * b4.z; acc[0][3] += a4.x * b4.w;
            acc[1][0] += a4.y * b4.x; acc[1][1] += a4.y * b4.y; acc[1][2] += a4.y * b4.z; acc[1][3] += a4.y * b4.w;
            acc[2][0] += a4.z * b4.x; acc[2][1] += a4.z * b4.y; acc[2][2] += a4.z * b4.z; acc[2][3] += a4.z * b4.w;
            acc[3][0] += a4.w * b4.x; acc[3][1] += a4.w * b4.y; acc[3][2] += a4.w * b4.z; acc[3][3] += a4.w * b4.w;
        }
    }
    float* Pb = P + (size_t)kc * NB * G3;
#pragma unroll
    for (int i = 0; i < 4; ++i) {
        float4 v = make_float4(acc[i][0], acc[i][1], acc[i][2], acc[i][3]);
        *(float4*)&Pb[(size_t)(tm4 + i) * G3 + col0 + tn4] = v;
    }
}

// FC: out[(b*39+t)*8192+v] = Hs[t][b][:] @ fc_W + fc_b   grid (39 t-tiles, 128 col-tiles)
__global__ __launch_bounds__(256) void k_fc(const float* __restrict__ Hs,
                                            const float* __restrict__ W,
                                            const float* __restrict__ bias,
                                            float* __restrict__ out)
{
    __shared__ float As[16][64];
    __shared__ float Bs[16][64];
    int tx = threadIdx.x;
    int tblk = blockIdx.x;               // decoder step
    int col0 = blockIdx.y * 64;
    int m_st = tx >> 2;
    int k_st = (tx & 3) * 4;
    int kb_st = tx >> 4;
    int nb_st = (tx & 15) * 4;
    int tn4 = (tx & 15) * 4;
    int tm4 = (tx >> 4) * 4;
    const float* Ab = Hs + (size_t)tblk * NB * NU + (size_t)m_st * NU + k_st;
    const float* Wb = W + (size_t)kb_st * NVO + col0 + nb_st;
    float acc[4][4] = {};
    for (int kk = 0; kk < 64; ++kk) {
        float4 av = *(const float4*)(Ab + kk * 16);
        float4 bv = *(const float4*)(Wb + (size_t)kk * 16 * NVO);
        __syncthreads();
        As[k_st + 0][m_st] = av.x;
        As[k_st + 1][m_st] = av.y;
        As[k_st + 2][m_st] = av.z;
        As[k_st + 3][m_st] = av.w;
        *(float4*)&Bs[kb_st][nb_st] = bv;
        __syncthreads();
#pragma unroll
        for (int k = 0; k < 16; ++k) {
            float4 a4 = *(const float4*)&As[k][tm4];
            float4 b4 = *(const float4*)&Bs[k][tn4];
            acc[0][0] += a4.x * b4.x; acc[0][1] += a4.x * b4.y; acc[0][2] += a4.x * b4.z; acc[0][3] += a4.x * b4.w;
            acc[1][0] += a4.y * b4.x; acc[1][1] += a4.y * b4.y; acc[1][2] += a4.y * b4.z; acc[1][3] += a4.y * b4.w;
            acc[2][0] += a4.z * b4.x; acc[2][1] += a4.z * b4.y; acc[2][2] += a4.z * b4.z; acc[2][3] += a4.z * b4.w;
            acc[3][0] += a4.w * b4.x; acc[3][1] += a4.w * b4.y; acc[3][2] += a4.w * b4.z; acc[3][3] += a4.w * b4.w;
        }
    }
    float4 bi = *(const float4*)(bias + col0 + tn4);
#pragma unroll
    for (int i = 0; i < 4; ++i) {
        int b = tm4 + i;
        float4 v = make_float4(acc[i][0] + bi.x, acc[i][1] + bi.y,
                               acc[i][2] + bi.z, acc[i][3] + bi.w);
        *(float4*)&out[((size_t)b * NT + tblk) * NVO + col0 + tn4] = v;
    }
}

// ---------------------------------------------------------------------------
// Gates + fused attention
// ---------------------------------------------------------------------------

__device__ __forceinline__ float sigmoidf_(float x) { return 1.0f / (1.0f + expf(-x)); }

__device__ __forceinline__ void attention_block(const float* __restrict__ enc_out,
                                                const float* __restrict__ h_sh,
                                                float* __restrict__ sc_sh,
                                                float* __restrict__ ctx,
                                                int b, int tx)
{
    int wave = tx >> 6, lane = tx & 63;
    const float* eb = enc_out + (size_t)b * NS * NU;
    for (int s = wave; s < NS; s += 4) {
        const float* es = eb + (size_t)s * NU;
        float p = 0.f;
        for (int k = lane; k < NU; k += 64) p += h_sh[k] * es[k];
        for (int off = 32; off > 0; off >>= 1) p += __shfl_down(p, off);
        if (lane == 0) sc_sh[s] = p;
    }
    __syncthreads();
    if (wave == 0) {
        float v = (lane < NS) ? sc_sh[lane] : -3.0e38f;
        float m = v;
        for (int off = 32; off > 0; off >>= 1) m = fmaxf(m, __shfl_down(m, off));
        m = __shfl(m, 0);
        float e = (lane < NS) ? expf(v - m) : 0.f;
        float ss = e;
        for (int off = 32; off > 0; off >>= 1) ss += __shfl_down(ss, off);
        ss = __shfl(ss, 0);
        if (lane < NS) sc_sh[lane] = e / ss;
    }
    __syncthreads();
    float* cb = ctx + (size_t)b * NU;
    for (int q = 0; q < 4; ++q) {
        int k = tx + q * 256;
        float c = 0.f;
#pragma unroll 8
        for (int s = 0; s < NS; ++s) c += sc_sh[s] * eb[(size_t)s * NU + k];
        cb[k] = c;
    }
}

// Encoder gates. grid(64)=b, block 256. Reduces split-K partials, applies GRU
// gates, writes h into enc_out[:,t,:]. For t==39 also computes attention ctx
// for decoder step 0.
__global__ __launch_bounds__(256) void k_enc_gates(const float* __restrict__ GX,
                                                   const float* __restrict__ P,
                                                   const float* __restrict__ b1,
                                                   const float* __restrict__ hprev, int hstride,
                                                   float* __restrict__ enc_out,
                                                   int t, int do_attn,
                                                   float* __restrict__ ctx)
{
    __shared__ float h_sh[NU];
    __shared__ float sc_sh[64];
    int tx = threadIdx.x;
    int b = blockIdx.x;
    const float* gx = GX + (size_t)(b * NS + t) * G3;
#pragma unroll
    for (int q = 0; q < 4; ++q) {
        int i = tx + q * 256;
        float sz = 0.f, sr = 0.f, sc = 0.f;
#pragma unroll
        for (int kc = 0; kc < 8; ++kc) {
            const float* Pb = P + ((size_t)kc * NB + b) * G3;
            sz += Pb[i];
            sr += Pb[NU + i];
            sc += Pb[2 * NU + i];
        }
        float ghz = sz + b1[i];
        float ghr = sr + b1[NU + i];
        float ghc = sc + b1[2 * NU + i];
        float z = sigmoidf_(gx[i] + ghz);
        float r = sigmoidf_(gx[NU + i] + ghr);
        float c = tanhf(gx[2 * NU + i] + r * ghc);
        float hp = hprev[(size_t)b * hstride + i];
        float hn = z * hp + (1.f - z) * c;
        enc_out[(size_t)b * NS * NU + (size_t)t * NU + i] = hn;
        h_sh[i] = hn;
    }
    if (do_attn) {
        __syncthreads();
        attention_block(enc_out, h_sh, sc_sh, ctx, b, tx);
    }
}

// Decoder gates (gh = dec_b[1] only; h_new = (1-z)*c). Writes Hs[t][b][:],
// and for t<38 computes attention ctx for the next step.
__global__ __launch_bounds__(256) void k_dec_gates(const float* __restrict__ GX,
                                                   const float* __restrict__ P,
                                                   const float* __restrict__ b1,
                                                   float* __restrict__ Hs,
                                                   int t, int do_attn,
                                                   const float* __restrict__ enc_out,
                                                   float* __restrict__ ctx)
{
    __shared__ float h_sh[NU];
    __shared__ float sc_sh[64];
    int tx = threadIdx.x;
    int b = blockIdx.x;
    const float* gx = GX + (size_t)(b * NT + t) * G3;
#pragma unroll
    for (int q = 0; q < 4; ++q) {
        int i = tx + q * 256;
        float sz = 0.f, sr = 0.f, sc = 0.f;
#pragma unroll
        for (int kc = 0; kc < 8; ++kc) {
            const float* Pb = P + ((size_t)kc * NB + b) * G3;
            sz += Pb[i];
            sr += Pb[NU + i];
            sc += Pb[2 * NU + i];
        }
        float z = sigmoidf_(gx[i] + sz + b1[i]);
        float r = sigmoidf_(gx[NU + i] + sr + b1[NU + i]);
        float c = tanhf(gx[2 * NU + i] + sc + r * b1[2 * NU + i]);
        float hn = (1.f - z) * c;
        Hs[((size_t)t * NB + b) * NU + i] = hn;
        h_sh[i] = hn;
    }
    if (do_attn) {
        __syncthreads();
        attention_block(enc_out, h_sh, sc_sh, ctx, b, tx);
    }
}

// ---------------------------------------------------------------------------

extern "C" void kernel_launch(void* const* d_in, const int* in_sizes, int n_in,
                              void* d_out, int out_size, void* d_ws, size_t ws_size,
                              hipStream_t stream)
{
    const int*   inp     = (const int*)d_in[0];
    const int*   targ    = (const int*)d_in[1];
    const float* enc_emb = (const float*)d_in[2];
    const float* enc_Wx  = (const float*)d_in[3];
    const float* enc_Wh  = (const float*)d_in[4];
    const float* enc_b   = (const float*)d_in[5];
    const float* dec_emb = (const float*)d_in[6];
    const float* dec_Wx  = (const float*)d_in[7];
    // d_in[8] = dec_Wh: unused (multiplied by h_zero == 0 in reference)
    const float* dec_b   = (const float*)d_in[9];
    const float* fc_W    = (const float*)d_in[10];
    const float* fc_b    = (const float*)d_in[11];
    float* out = (float*)d_out;

    float* ws = (float*)d_ws;
    float* gx_buf  = ws;                      // 7,864,320 (enc GX, then dec GX)
    float* enc_out = gx_buf  + 7864320;       // 2,621,440  [b][s][u]
    float* Hs      = enc_out + 2621440;       // 2,555,904  [t][b][u]
    float* ctx     = Hs      + 2555904;       //    65,536  [b][u]
    float* hz      = ctx     + 65536;         //    65,536  zeros
    float* P       = hz      + 65536;         // 1,572,864  [8][b][3u]

    hipMemsetAsync(hz, 0, (size_t)NB * NU * sizeof(float), stream);

    // Encoder x-path: GXe[b*40+s][j] = emb[inp] @ enc_Wx + enc_b[0]
    k_gx<<<dim3(40, 48), 256, 0, stream>>>(inp, 40, 40, enc_emb, enc_Wx, enc_b, gx_buf);

    // Encoder scan
    for (int t = 0; t < NS; ++t) {
        const float* hprev = (t == 0) ? hz : (enc_out + (size_t)(t - 1) * NU);
        int hstride = (t == 0) ? NU : (NS * NU);
        k_part<<<dim3(48, 8), 256, 0, stream>>>(hprev, hstride, enc_Wh, P);
        k_enc_gates<<<64, 256, 0, stream>>>(gx_buf, P, enc_b + G3, hprev, hstride,
                                            enc_out, t, (t == NS - 1) ? 1 : 0, ctx);
    }

    // Decoder x-path: GXd[b*39+t][j] = emb[targ[:, :39]] @ dec_Wx[U:] + dec_b[0]
    k_gx<<<dim3(39, 48), 256, 0, stream>>>(targ, 40, 39, dec_emb,
                                           dec_Wx + (size_t)NU * G3, dec_b, gx_buf);

    // Decoder scan (ctx for t=0 produced by k_enc_gates at t=39)
    for (int t = 0; t < NT; ++t) {
        k_part<<<dim3(48, 8), 256, 0, stream>>>(ctx, NU, dec_Wx, P);
        k_dec_gates<<<64, 256, 0, stream>>>(gx_buf, P, dec_b + G3, Hs,
                                            t, (t < NT - 1) ? 1 : 0, enc_out, ctx);
    }

    // FC head: one batched GEMM over all 39 steps
    k_fc<<<dim3(39, 128), 256, 0, stream>>>(Hs, fc_W, fc_b, out);
}

// Round 2
// 3808.678 us; speedup vs baseline: 1.0193x; 1.0193x over previous
//
#include <hip/hip_runtime.h>
#include <hip/hip_bf16.h>

#define NB 64      // batch
#define NS 40      // src len
#define NT 39      // tgt steps (T-1)
#define NE 256     // emb
#define NU 1024    // hidden
#define G3 3072    // 3*U
#define NVO 8192
#define KC 8       // split-K chunks for the recurrent GEMM

typedef __attribute__((ext_vector_type(8))) short short8_t;   // 8 x bf16 frag
typedef __attribute__((ext_vector_type(4))) float float4_t;   // 4 x f32 acc

// ---------------------------------------------------------------------------
// bf16 helpers (RNE)
// ---------------------------------------------------------------------------
__device__ __forceinline__ unsigned short f2bf(float x) {
    union { float f; unsigned u; } v; v.f = x;
    unsigned r = v.u + 0x7fffu + ((v.u >> 16) & 1u);
    return (unsigned short)(r >> 16);
}
__device__ __forceinline__ float bf2f(unsigned short h) {
    union { float f; unsigned u; } v; v.u = ((unsigned)h) << 16; return v.f;
}
__device__ __forceinline__ float sigmoidf_(float x) { return 1.0f / (1.0f + expf(-x)); }

// ---------------------------------------------------------------------------
// Pack a K x N fp32 weight matrix into MFMA B-fragment order, hi/lo bf16.
// Element W[k][n] with n = nt*16 + (l&15), k = s*32 + (l>>4)*8 + j goes to
// Bp[((nt*(K/32) + s)*64 + l)*8 + j]  (lo plane at +planeOff ushorts).
// grid (N/16, K/32), block 64.
// ---------------------------------------------------------------------------
__global__ __launch_bounds__(64) void k_pack_b(const float* __restrict__ W, int N,
                                               unsigned short* __restrict__ Bp, int planeOff)
{
    int nt = blockIdx.x, s = blockIdx.y;
    int l = threadIdx.x;
    int n = nt * 16 + (l & 15);
    int k0 = s * 32 + (l >> 4) * 8;
    size_t obase = (((size_t)nt * gridDim.y + s) * 64 + l) * 8;
#pragma unroll
    for (int j = 0; j < 8; ++j) {
        float x = W[(size_t)(k0 + j) * N + n];
        unsigned short h = f2bf(x);
        Bp[obase + j] = h;
        Bp[planeOff + obase + j] = f2bf(x - bf2f(h));
    }
}

// ---------------------------------------------------------------------------
// Recurrent-step GEMM: P[kc][m][n] = sum_{k in chunk} A[m][k] * W[k][n]
// A: plain bf16 hi/lo [64][1024]. B: packed fragment order.
// grid (96 n-blocks of 32, KC k-chunks of 1024/KC), block 256 (4 waves).
// bf16x3: hi*hi + hi*lo + lo*hi, fp32 MFMA accumulate. No LDS, no barriers.
// ---------------------------------------------------------------------------
__global__ __launch_bounds__(256) void k_step(const unsigned short* __restrict__ Ah,
                                              const unsigned short* __restrict__ Al,
                                              const unsigned short* __restrict__ Bp,
                                              float* __restrict__ P)
{
    const int PO = (G3 / 16) * (NU / 32) * 512;   // plane offset (ushorts)
    int tx = threadIdx.x;
    int w = tx >> 6, l = tx & 63;
    int lq = l >> 4, lr = l & 15;
    int nb = blockIdx.x;         // 0..95 -> col0 = nb*32
    int kc = blockIdx.y;         // 0..KC-1
    int m0 = w * 16;
    float4_t acc0 = {0.f, 0.f, 0.f, 0.f};
    float4_t acc1 = {0.f, 0.f, 0.f, 0.f};
    int arow = (m0 + lr) * NU + lq * 8;
    size_t bb0 = ((size_t)(nb * 2 + 0) * (NU / 32)) * 512 + l * 8;
    size_t bb1 = ((size_t)(nb * 2 + 1) * (NU / 32)) * 512 + l * 8;
    const int SS = (NU / 32) / KC;   // k-steps per chunk
#pragma unroll
    for (int ss = 0; ss < SS; ++ss) {
        int s = kc * SS + ss;
        short8_t ah = *(const short8_t*)(Ah + arow + s * 32);
        short8_t al = *(const short8_t*)(Al + arow + s * 32);
        short8_t bh0 = *(const short8_t*)(Bp + bb0 + (size_t)s * 512);
        short8_t bl0 = *(const short8_t*)(Bp + PO + bb0 + (size_t)s * 512);
        short8_t bh1 = *(const short8_t*)(Bp + bb1 + (size_t)s * 512);
        short8_t bl1 = *(const short8_t*)(Bp + PO + bb1 + (size_t)s * 512);
        acc0 = __builtin_amdgcn_mfma_f32_16x16x32_bf16(ah, bh0, acc0, 0, 0, 0);
        acc0 = __builtin_amdgcn_mfma_f32_16x16x32_bf16(ah, bl0, acc0, 0, 0, 0);
        acc0 = __builtin_amdgcn_mfma_f32_16x16x32_bf16(al, bh0, acc0, 0, 0, 0);
        acc1 = __builtin_amdgcn_mfma_f32_16x16x32_bf16(ah, bh1, acc1, 0, 0, 0);
        acc1 = __builtin_amdgcn_mfma_f32_16x16x32_bf16(ah, bl1, acc1, 0, 0, 0);
        acc1 = __builtin_amdgcn_mfma_f32_16x16x32_bf16(al, bh1, acc1, 0, 0, 0);
    }
    float* Pb = P + (size_t)kc * NB * G3;
    int col0 = nb * 32;
#pragma unroll
    for (int r = 0; r < 4; ++r) {
        int m = m0 + lq * 4 + r;
        Pb[(size_t)m * G3 + col0 + lr]      = acc0[r];
        Pb[(size_t)m * G3 + col0 + 16 + lr] = acc1[r];
    }
}

// ---------------------------------------------------------------------------
// FC: out[(b*39+t)*8192+v] = Hs[t*64+b][:] @ fc_W + fc_b, bf16x3 MFMA.
// grid (39, 128), block 256 (4 waves); per wave 16 rows x 64 cols, K=1024.
// ---------------------------------------------------------------------------
__global__ __launch_bounds__(256) void k_fc_mfma(const unsigned short* __restrict__ Ah,
                                                 const unsigned short* __restrict__ Al,
                                                 const unsigned short* __restrict__ Bp,
                                                 const float* __restrict__ bias,
                                                 float* __restrict__ out)
{
    const int PO = (NVO / 16) * (NU / 32) * 512;
    int tx = threadIdx.x;
    int w = tx >> 6, l = tx & 63;
    int lq = l >> 4, lr = l & 15;
    int t = blockIdx.x;
    int cb = blockIdx.y;
    int m0 = t * 64 + w * 16;
    float4_t acc[4] = {{0.f,0.f,0.f,0.f},{0.f,0.f,0.f,0.f},{0.f,0.f,0.f,0.f},{0.f,0.f,0.f,0.f}};
    int arow = (m0 + lr) * NU + lq * 8;
    size_t bb = ((size_t)cb * 4 * (NU / 32)) * 512 + l * 8;
#pragma unroll 2
    for (int s = 0; s < NU / 32; ++s) {
        short8_t ah = *(const short8_t*)(Ah + arow + s * 32);
        short8_t al = *(const short8_t*)(Al + arow + s * 32);
#pragma unroll
        for (int nf = 0; nf < 4; ++nf) {
            const unsigned short* bp = Bp + bb + (size_t)nf * (NU / 32) * 512 + (size_t)s * 512;
            short8_t bh = *(const short8_t*)bp;
            short8_t bl = *(const short8_t*)(bp + PO);
            acc[nf] = __builtin_amdgcn_mfma_f32_16x16x32_bf16(ah, bh, acc[nf], 0, 0, 0);
            acc[nf] = __builtin_amdgcn_mfma_f32_16x16x32_bf16(ah, bl, acc[nf], 0, 0, 0);
            acc[nf] = __builtin_amdgcn_mfma_f32_16x16x32_bf16(al, bh, acc[nf], 0, 0, 0);
        }
    }
    int col0 = cb * 64;
#pragma unroll
    for (int nf = 0; nf < 4; ++nf) {
        int v = col0 + nf * 16 + lr;
        float bi = bias[v];
#pragma unroll
        for (int r = 0; r < 4; ++r) {
            int brow = w * 16 + lq * 4 + r;   // batch index
            out[((size_t)brow * NT + t) * NVO + v] = acc[nf][r] + bi;
        }
    }
}

// ---------------------------------------------------------------------------
// GX = gather(emb, idx) @ W(256 x 3072) + bias (fp32, as round 1)
// ---------------------------------------------------------------------------
__global__ __launch_bounds__(256) void k_gx(const int* __restrict__ idx,
                                            int cols_total, int cols_used,
                                            const float* __restrict__ emb,
                                            const float* __restrict__ W,
                                            const float* __restrict__ bias,
                                            float* __restrict__ out)
{
    __shared__ float As[16][64];
    __shared__ float Bs[16][64];
    __shared__ int tok_sh[64];
    int tx = threadIdx.x;
    int row0 = blockIdx.x * 64;
    int col0 = blockIdx.y * 64;
    if (tx < 64) {
        int row = row0 + tx;
        int b = row / cols_used;
        int c = row - b * cols_used;
        tok_sh[tx] = idx[b * cols_total + c];
    }
    __syncthreads();
    int m_st = tx >> 2;
    int k_st = (tx & 3) * 4;
    int kb_st = tx >> 4;
    int nb_st = (tx & 15) * 4;
    int tn4 = (tx & 15) * 4;
    int tm4 = (tx >> 4) * 4;
    int tok = tok_sh[m_st];
    const float* Ab = emb + tok * NE + k_st;
    const float* Wb = W + kb_st * G3 + col0 + nb_st;
    float acc[4][4] = {};
    for (int kk = 0; kk < 16; ++kk) {
        float4 av = *(const float4*)(Ab + kk * 16);
        float4 bv = *(const float4*)(Wb + (size_t)kk * 16 * G3);
        __syncthreads();
        As[k_st + 0][m_st] = av.x;
        As[k_st + 1][m_st] = av.y;
        As[k_st + 2][m_st] = av.z;
        As[k_st + 3][m_st] = av.w;
        *(float4*)&Bs[kb_st][nb_st] = bv;
        __syncthreads();
#pragma unroll
        for (int k = 0; k < 16; ++k) {
            float4 a4 = *(const float4*)&As[k][tm4];
            float4 b4 = *(const float4*)&Bs[k][tn4];
            acc[0][0] += a4.x * b4.x; acc[0][1] += a4.x * b4.y; acc[0][2] += a4.x * b4.z; acc[0][3] += a4.x * b4.w;
            acc[1][0] += a4.y * b4.x; acc[1][1] += a4.y * b4.y; acc[1][2] += a4.y * b4.z; acc[1][3] += a4.y * b4.w;
            acc[2][0] += a4.z * b4.x; acc[2][1] += a4.z * b4.y; acc[2][2] += a4.z * b4.z; acc[2][3] += a4.z * b4.w;
            acc[3][0] += a4.w * b4.x; acc[3][1] += a4.w * b4.y; acc[3][2] += a4.w * b4.z; acc[3][3] += a4.w * b4.w;
        }
    }
    float4 bi = *(const float4*)(bias + col0 + tn4);
#pragma unroll
    for (int i = 0; i < 4; ++i) {
        float4 v = make_float4(acc[i][0] + bi.x, acc[i][1] + bi.y,
                               acc[i][2] + bi.z, acc[i][3] + bi.w);
        *(float4*)&out[(size_t)(row0 + tm4 + i) * G3 + col0 + tn4] = v;
    }
}

// ---------------------------------------------------------------------------
// Fused attention: scores -> softmax -> ctx (hi/lo bf16 out)
// ---------------------------------------------------------------------------
__device__ __forceinline__ void attention_block(const float* __restrict__ enc_out,
                                                const float* __restrict__ h_sh,
                                                float* __restrict__ sc_sh,
                                                unsigned short* __restrict__ ctx_hi,
                                                unsigned short* __restrict__ ctx_lo,
                                                int b, int tx)
{
    int wave = tx >> 6, lane = tx & 63;
    const float* eb = enc_out + (size_t)b * NS * NU;
    for (int s = wave; s < NS; s += 4) {
        const float* es = eb + (size_t)s * NU;
        float p = 0.f;
        for (int k = lane; k < NU; k += 64) p += h_sh[k] * es[k];
        for (int off = 32; off > 0; off >>= 1) p += __shfl_down(p, off);
        if (lane == 0) sc_sh[s] = p;
    }
    __syncthreads();
    if (wave == 0) {
        float v = (lane < NS) ? sc_sh[lane] : -3.0e38f;
        float m = v;
        for (int off = 32; off > 0; off >>= 1) m = fmaxf(m, __shfl_down(m, off));
        m = __shfl(m, 0);
        float e = (lane < NS) ? expf(v - m) : 0.f;
        float ss = e;
        for (int off = 32; off > 0; off >>= 1) ss += __shfl_down(ss, off);
        ss = __shfl(ss, 0);
        if (lane < NS) sc_sh[lane] = e / ss;
    }
    __syncthreads();
    for (int q = 0; q < 4; ++q) {
        int k = tx + q * 256;
        float c = 0.f;
#pragma unroll 8
        for (int s = 0; s < NS; ++s) c += sc_sh[s] * eb[(size_t)s * NU + k];
        unsigned short h = f2bf(c);
        ctx_hi[(size_t)b * NU + k] = h;
        ctx_lo[(size_t)b * NU + k] = f2bf(c - bf2f(h));
    }
}

// Encoder gates: reduce split-K partials, GRU gates, write h (fp32 enc_out +
// bf16 hi/lo planes for next step's GEMM). Last step computes attention ctx.
__global__ __launch_bounds__(256) void k_enc_gates(const float* __restrict__ GX,
                                                   const float* __restrict__ P,
                                                   const float* __restrict__ b1,
                                                   const float* __restrict__ hprev, int hstride,
                                                   float* __restrict__ enc_out,
                                                   unsigned short* __restrict__ h_hi,
                                                   unsigned short* __restrict__ h_lo,
                                                   int t, int do_attn,
                                                   unsigned short* __restrict__ ctx_hi,
                                                   unsigned short* __restrict__ ctx_lo)
{
    __shared__ float h_sh[NU];
    __shared__ float sc_sh[64];
    int tx = threadIdx.x;
    int b = blockIdx.x;
    const float* gx = GX + (size_t)(b * NS + t) * G3;
#pragma unroll
    for (int q = 0; q < 4; ++q) {
        int i = tx + q * 256;
        float sz = 0.f, sr = 0.f, sc = 0.f;
#pragma unroll
        for (int kc = 0; kc < KC; ++kc) {
            const float* Pb = P + ((size_t)kc * NB + b) * G3;
            sz += Pb[i];
            sr += Pb[NU + i];
            sc += Pb[2 * NU + i];
        }
        float z = sigmoidf_(gx[i] + sz + b1[i]);
        float r = sigmoidf_(gx[NU + i] + sr + b1[NU + i]);
        float c = tanhf(gx[2 * NU + i] + r * (sc + b1[2 * NU + i]));
        float hp = hprev[(size_t)b * hstride + i];
        float hn = z * hp + (1.f - z) * c;
        enc_out[(size_t)b * NS * NU + (size_t)t * NU + i] = hn;
        unsigned short hh = f2bf(hn);
        h_hi[(size_t)b * NU + i] = hh;
        h_lo[(size_t)b * NU + i] = f2bf(hn - bf2f(hh));
        h_sh[i] = hn;
    }
    if (do_attn) {
        __syncthreads();
        attention_block(enc_out, h_sh, sc_sh, ctx_hi, ctx_lo, b, tx);
    }
}

// Decoder gates (gh = dec_b[1] only; h_new = (1-z)*c). Writes Hs hi/lo planes
// (FC input) and attention ctx for the next step.
__global__ __launch_bounds__(256) void k_dec_gates(const float* __restrict__ GX,
                                                   const float* __restrict__ P,
                                                   const float* __restrict__ b1,
                                                   unsigned short* __restrict__ Hs_hi,
                                                   unsigned short* __restrict__ Hs_lo,
                                                   int t, int do_attn,
                                                   const float* __restrict__ enc_out,
                                                   unsigned short* __restrict__ ctx_hi,
                                                   unsigned short* __restrict__ ctx_lo)
{
    __shared__ float h_sh[NU];
    __shared__ float sc_sh[64];
    int tx = threadIdx.x;
    int b = blockIdx.x;
    const float* gx = GX + (size_t)(b * NT + t) * G3;
#pragma unroll
    for (int q = 0; q < 4; ++q) {
        int i = tx + q * 256;
        float sz = 0.f, sr = 0.f, sc = 0.f;
#pragma unroll
        for (int kc = 0; kc < KC; ++kc) {
            const float* Pb = P + ((size_t)kc * NB + b) * G3;
            sz += Pb[i];
            sr += Pb[NU + i];
            sc += Pb[2 * NU + i];
        }
        float z = sigmoidf_(gx[i] + sz + b1[i]);
        float r = sigmoidf_(gx[NU + i] + sr + b1[NU + i]);
        float c = tanhf(gx[2 * NU + i] + sc + r * b1[2 * NU + i]);
        float hn = (1.f - z) * c;
        size_t row = (size_t)t * NB + b;
        unsigned short hh = f2bf(hn);
        Hs_hi[row * NU + i] = hh;
        Hs_lo[row * NU + i] = f2bf(hn - bf2f(hh));
        h_sh[i] = hn;
    }
    if (do_attn) {
        __syncthreads();
        attention_block(enc_out, h_sh, sc_sh, ctx_hi, ctx_lo, b, tx);
    }
}

// ---------------------------------------------------------------------------

extern "C" void kernel_launch(void* const* d_in, const int* in_sizes, int n_in,
                              void* d_out, int out_size, void* d_ws, size_t ws_size,
                              hipStream_t stream)
{
    const int*   inp     = (const int*)d_in[0];
    const int*   targ    = (const int*)d_in[1];
    const float* enc_emb = (const float*)d_in[2];
    const float* enc_Wx  = (const float*)d_in[3];
    const float* enc_Wh  = (const float*)d_in[4];
    const float* enc_b   = (const float*)d_in[5];
    const float* dec_emb = (const float*)d_in[6];
    const float* dec_Wx  = (const float*)d_in[7];
    // d_in[8] = dec_Wh: unused (multiplied by h_zero == 0 in reference)
    const float* dec_b   = (const float*)d_in[9];
    const float* fc_W    = (const float*)d_in[10];
    const float* fc_b    = (const float*)d_in[11];
    float* out = (float*)d_out;

    // ---- workspace carve (bytes) ----
    char* ws = (char*)d_ws;
    // R1: gx (31.46 MB) during scans, then Bp_fc (33.55 MB) for the FC GEMM
    float*          gx_buf  = (float*)ws;
    unsigned short* Bp_fc   = (unsigned short*)ws;
    char* p = ws + 33554432;
    float* enc_out = (float*)p;              p += 10485760;   // [b][s][u] fp32
    float* Pp      = (float*)p;              p += (size_t)KC * NB * G3 * 4;  // 6.29 MB
    float* hz      = (float*)p;              p += 262144;     // fp32 zeros (t=0 hprev)
    unsigned short* h_hi   = (unsigned short*)p; p += 131072;
    unsigned short* h_lo   = (unsigned short*)p; p += 131072;
    unsigned short* ctx_hi = (unsigned short*)p; p += 131072;
    unsigned short* ctx_lo = (unsigned short*)p; p += 131072;
    unsigned short* Hs_hi  = (unsigned short*)p; p += 5111808;
    unsigned short* Hs_lo  = (unsigned short*)p; p += 5111808;
    unsigned short* Bp_enc = (unsigned short*)p; p += 12582912;
    unsigned short* Bp_dec = (unsigned short*)p; p += 12582912;

    const int PO_STEP = (G3 / 16) * (NU / 32) * 512;    // 3,145,728 ushorts
    const int PO_FC   = (NVO / 16) * (NU / 32) * 512;   // 8,388,608 ushorts

    // zero hz + h_hi + h_lo (contiguous) in one shot
    hipMemsetAsync(hz, 0, 262144 + 131072 + 131072, stream);

    // pack recurrent weights (hi/lo bf16, fragment order)
    k_pack_b<<<dim3(G3 / 16, NU / 32), 64, 0, stream>>>(enc_Wh, G3, Bp_enc, PO_STEP);
    k_pack_b<<<dim3(G3 / 16, NU / 32), 64, 0, stream>>>(dec_Wx, G3, Bp_dec, PO_STEP);

    // Encoder x-path (fp32)
    k_gx<<<dim3(40, 48), 256, 0, stream>>>(inp, 40, 40, enc_emb, enc_Wx, enc_b, gx_buf);

    // Encoder scan
    for (int t = 0; t < NS; ++t) {
        const float* hprev = (t == 0) ? hz : (enc_out + (size_t)(t - 1) * NU);
        int hstride = (t == 0) ? NU : (NS * NU);
        k_step<<<dim3(96, KC), 256, 0, stream>>>(h_hi, h_lo, Bp_enc, Pp);
        k_enc_gates<<<64, 256, 0, stream>>>(gx_buf, Pp, enc_b + G3, hprev, hstride,
                                            enc_out, h_hi, h_lo,
                                            t, (t == NS - 1) ? 1 : 0, ctx_hi, ctx_lo);
    }

    // Decoder x-path (fp32): emb[targ[:, :39]] @ dec_Wx[U:] + dec_b[0]
    k_gx<<<dim3(39, 48), 256, 0, stream>>>(targ, 40, 39, dec_emb,
                                           dec_Wx + (size_t)NU * G3, dec_b, gx_buf);

    // Decoder scan (ctx for t=0 produced by k_enc_gates at t=39)
    for (int t = 0; t < NT; ++t) {
        k_step<<<dim3(96, KC), 256, 0, stream>>>(ctx_hi, ctx_lo, Bp_dec, Pp);
        k_dec_gates<<<64, 256, 0, stream>>>(gx_buf, Pp, dec_b + G3, Hs_hi, Hs_lo,
                                            t, (t < NT - 1) ? 1 : 0, enc_out, ctx_hi, ctx_lo);
    }

    // FC head: pack fc_W into R1 (gx dead now), then one batched MFMA GEMM
    k_pack_b<<<dim3(NVO / 16, NU / 32), 64, 0, stream>>>(fc_W, NVO, Bp_fc, PO_FC);
    k_fc_mfma<<<dim3(NT, NVO / 64), 256, 0, stream>>>(Hs_hi, Hs_lo, Bp_fc, fc_b, out);
}

// Round 3
// 2839.434 us; speedup vs baseline: 1.3672x; 1.3414x over previous
//
#include <hip/hip_runtime.h>
#include <hip/hip_bf16.h>

#define NB 64      // batch
#define NS 40      // src len
#define NT 39      // tgt steps (T-1)
#define NE 256     // emb
#define NU 1024    // hidden
#define G3 3072    // 3*U
#define NVO 8192

typedef __attribute__((ext_vector_type(8))) short short8_t;   // 8 x bf16 frag
typedef __attribute__((ext_vector_type(4))) float float4_t;   // 4 x f32 acc

// plane offsets (ushort counts)
#define PO_S  3145728   // step weights: 64 blk * 96 * 64 * 8
#define PO_GX 786432    // gx weights: 192 * 8 * 64 * 8
#define PO_FC 8388608   // fc weights: 512 * 32 * 64 * 8

// ---------------------------------------------------------------------------
__device__ __forceinline__ unsigned short f2bf(float x) {
    union { float f; unsigned u; } v; v.f = x;
    unsigned r = v.u + 0x7fffu + ((v.u >> 16) & 1u);
    return (unsigned short)(r >> 16);
}
__device__ __forceinline__ float bf2f(unsigned short h) {
    union { float f; unsigned u; } v; v.u = ((unsigned)h) << 16; return v.f;
}
__device__ __forceinline__ float sigmoidf_(float x) { return 1.0f / (1.0f + expf(-x)); }

// ---------------------------------------------------------------------------
// Generic packer: K x N fp32 -> MFMA B-frag order hi/lo. grid (N/16, K/32).
// frag (nt, s): Bp[((nt*(K/32)+s)*64 + l)*8 + j] = W[s*32+(l>>4)*8+j][nt*16+(l&15)]
// ---------------------------------------------------------------------------
__global__ __launch_bounds__(64) void k_pack_b(const float* __restrict__ W, int N,
                                               unsigned short* __restrict__ Bp, int planeOff)
{
    int nt = blockIdx.x, s = blockIdx.y;
    int l = threadIdx.x;
    int n = nt * 16 + (l & 15);
    int k0 = s * 32 + (l >> 4) * 8;
    size_t ob = (((size_t)nt * gridDim.y + s) * 64 + l) * 8;
#pragma unroll
    for (int jj = 0; jj < 8; ++jj) {
        float x = W[(size_t)(k0 + jj) * N + n];
        unsigned short h = f2bf(x);
        Bp[ob + jj] = h;
        Bp[planeOff + ob + jj] = f2bf(x - bf2f(h));
    }
}

// Step-weight packer: block j of the step kernel owns cols {g*1024 + 16j..+16}.
// Layout: Bp[(((j*96) + g*32 + s)*64 + l)*8 + jj]. grid (64, 96=g*32+s).
__global__ __launch_bounds__(64) void k_pack_step(const float* __restrict__ W,
                                                  unsigned short* __restrict__ Bp)
{
    int j = blockIdx.x;
    int q = blockIdx.y;            // g*32 + s
    int g = q >> 5, s = q & 31;
    int l = threadIdx.x;
    int n = g * NU + j * 16 + (l & 15);
    int k0 = s * 32 + (l >> 4) * 8;
    size_t ob = (((size_t)j * 96 + q) * 64 + l) * 8;
#pragma unroll
    for (int jj = 0; jj < 8; ++jj) {
        float x = W[(size_t)(k0 + jj) * G3 + n];
        unsigned short h = f2bf(x);
        Bp[ob + jj] = h;
        Bp[PO_S + ob + jj] = f2bf(x - bf2f(h));
    }
}

// Gather embeddings -> bf16 plane. grid (rows), block 256 (= NE).
__global__ __launch_bounds__(256) void k_gather(const int* __restrict__ idx,
                                                int cols_total, int cols_used,
                                                const float* __restrict__ emb,
                                                unsigned short* __restrict__ Ax)
{
    int row = blockIdx.x;
    int b = row / cols_used, c = row - b * cols_used;
    int tok = idx[b * cols_total + c];
    int k = threadIdx.x;
    Ax[(size_t)row * NE + k] = f2bf(emb[(size_t)tok * NE + k]);
}

// GX GEMM: out[row][col] = Ax[row][:256] @ W + bias. grid (M/64, 48), block 256.
// A single-plane bf16 (error ~1e-5 in gx — negligible), B hi/lo.
__global__ __launch_bounds__(256) void k_gx_mfma(const unsigned short* __restrict__ Ax,
                                                 const unsigned short* __restrict__ Bp,
                                                 const float* __restrict__ bias,
                                                 float* __restrict__ out)
{
    int tx = threadIdx.x;
    int w = tx >> 6, l = tx & 63;
    int lq = l >> 4, lr = l & 15;
    int row0 = blockIdx.x * 64 + w * 16;
    int cb = blockIdx.y;                       // 48 n-blocks of 64
    float4_t acc[4] = {{0,0,0,0},{0,0,0,0},{0,0,0,0},{0,0,0,0}};
    const unsigned short* Ab = Ax + (size_t)(row0 + lr) * NE + lq * 8;
#pragma unroll
    for (int s = 0; s < 8; ++s) {
        short8_t ah = *(const short8_t*)(Ab + s * 32);
#pragma unroll
        for (int nf = 0; nf < 4; ++nf) {
            const unsigned short* bp = Bp + ((((size_t)cb * 4 + nf) * 8 + s) * 64 + l) * 8;
            short8_t bh = *(const short8_t*)bp;
            short8_t bl = *(const short8_t*)(bp + PO_GX);
            acc[nf] = __builtin_amdgcn_mfma_f32_16x16x32_bf16(ah, bh, acc[nf], 0, 0, 0);
            acc[nf] = __builtin_amdgcn_mfma_f32_16x16x32_bf16(ah, bl, acc[nf], 0, 0, 0);
        }
    }
#pragma unroll
    for (int nf = 0; nf < 4; ++nf) {
        int col = cb * 64 + nf * 16 + lr;
        float bi = bias[col];
#pragma unroll
        for (int r = 0; r < 4; ++r) {
            int gr = row0 + lq * 4 + r;
            out[(size_t)gr * G3 + col] = acc[nf][r] + bi;
        }
    }
}

// ---------------------------------------------------------------------------
// Fused encoder step: block j owns cols 16j..16j+16 of each gate.
// 16 waves: wave = (kw = w>>2) K-chunk of 256, (mw = w&3) 16 rows.
// LDS reduce -> gates -> write h slice. One kernel per step, no split-K buffer.
// ---------------------------------------------------------------------------
__global__ __launch_bounds__(1024) void k_enc_step(
    const unsigned short* __restrict__ Ah, const unsigned short* __restrict__ Al,
    const unsigned short* __restrict__ Bp,
    const float* __restrict__ GX, const float* __restrict__ b1,
    float* __restrict__ enc_out,
    unsigned short* __restrict__ Oh, unsigned short* __restrict__ Ol,
    int t)
{
    __shared__ float red[4][4][3][256];        // [kw][mw][g][16x16]
    int tx = threadIdx.x;
    int j = blockIdx.x;
    int w = tx >> 6, l = tx & 63;
    int lq = l >> 4, lr = l & 15;
    int mw = w & 3, kw = w >> 2;
    float4_t acc[3] = {{0,0,0,0},{0,0,0,0},{0,0,0,0}};
    const unsigned short* Ab  = Ah + (size_t)(mw * 16 + lr) * NU + kw * 256 + lq * 8;
    const unsigned short* Alb = Al + (size_t)(mw * 16 + lr) * NU + kw * 256 + lq * 8;
    const unsigned short* Bb  = Bp + (size_t)j * 96 * 512 + l * 8;
#pragma unroll
    for (int sl = 0; sl < 8; ++sl) {
        int sg = kw * 8 + sl;
        short8_t ah = *(const short8_t*)(Ab + sl * 32);
        short8_t al = *(const short8_t*)(Alb + sl * 32);
#pragma unroll
        for (int g = 0; g < 3; ++g) {
            const unsigned short* bp = Bb + (size_t)(g * 32 + sg) * 512;
            short8_t bh = *(const short8_t*)bp;
            short8_t bl = *(const short8_t*)(bp + PO_S);
            acc[g] = __builtin_amdgcn_mfma_f32_16x16x32_bf16(ah, bh, acc[g], 0, 0, 0);
            acc[g] = __builtin_amdgcn_mfma_f32_16x16x32_bf16(ah, bl, acc[g], 0, 0, 0);
            acc[g] = __builtin_amdgcn_mfma_f32_16x16x32_bf16(al, bh, acc[g], 0, 0, 0);
        }
    }
#pragma unroll
    for (int g = 0; g < 3; ++g)
#pragma unroll
        for (int r = 0; r < 4; ++r)
            red[kw][mw][g][(lq * 4 + r) * 16 + lr] = acc[g][r];
    __syncthreads();
    // epilogue: 1024 threads = 64 rows x 16 cols
    int b = tx >> 4, c = tx & 15;
    int mw2 = b >> 4, ml = b & 15;
    float gz = 0.f, gr_ = 0.f, gc = 0.f;
#pragma unroll
    for (int k2 = 0; k2 < 4; ++k2) {
        gz  += red[k2][mw2][0][ml * 16 + c];
        gr_ += red[k2][mw2][1][ml * 16 + c];
        gc  += red[k2][mw2][2][ml * 16 + c];
    }
    int col = j * 16 + c;
    const float* gx = GX + ((size_t)b * NS + t) * G3 + col;
    float z = sigmoidf_(gx[0]      + gz  + b1[col]);
    float r = sigmoidf_(gx[NU]     + gr_ + b1[NU + col]);
    float cc = tanhf(gx[2 * NU] + r * (gc + b1[2 * NU + col]));
    float hp = bf2f(Ah[(size_t)b * NU + col]) + bf2f(Al[(size_t)b * NU + col]);
    float hn = z * hp + (1.f - z) * cc;
    enc_out[(size_t)b * NS * NU + (size_t)t * NU + col] = hn;
    unsigned short hh = f2bf(hn);
    Oh[(size_t)b * NU + col] = hh;
    Ol[(size_t)b * NU + col] = f2bf(hn - bf2f(hh));
}

// Fused decoder step: A = ctx hi/lo; gh = dec_b[1]; h = (1-z)*c.
// Writes hdec fp32 (for attention) and Hs hi/lo (FC input).
__global__ __launch_bounds__(1024) void k_dec_step(
    const unsigned short* __restrict__ Ah, const unsigned short* __restrict__ Al,
    const unsigned short* __restrict__ Bp,
    const float* __restrict__ GX, const float* __restrict__ b1,
    float* __restrict__ hdec,
    unsigned short* __restrict__ Hs_hi, unsigned short* __restrict__ Hs_lo,
    int t)
{
    __shared__ float red[4][4][3][256];
    int tx = threadIdx.x;
    int j = blockIdx.x;
    int w = tx >> 6, l = tx & 63;
    int lq = l >> 4, lr = l & 15;
    int mw = w & 3, kw = w >> 2;
    float4_t acc[3] = {{0,0,0,0},{0,0,0,0},{0,0,0,0}};
    const unsigned short* Ab  = Ah + (size_t)(mw * 16 + lr) * NU + kw * 256 + lq * 8;
    const unsigned short* Alb = Al + (size_t)(mw * 16 + lr) * NU + kw * 256 + lq * 8;
    const unsigned short* Bb  = Bp + (size_t)j * 96 * 512 + l * 8;
#pragma unroll
    for (int sl = 0; sl < 8; ++sl) {
        int sg = kw * 8 + sl;
        short8_t ah = *(const short8_t*)(Ab + sl * 32);
        short8_t al = *(const short8_t*)(Alb + sl * 32);
#pragma unroll
        for (int g = 0; g < 3; ++g) {
            const unsigned short* bp = Bb + (size_t)(g * 32 + sg) * 512;
            short8_t bh = *(const short8_t*)bp;
            short8_t bl = *(const short8_t*)(bp + PO_S);
            acc[g] = __builtin_amdgcn_mfma_f32_16x16x32_bf16(ah, bh, acc[g], 0, 0, 0);
            acc[g] = __builtin_amdgcn_mfma_f32_16x16x32_bf16(ah, bl, acc[g], 0, 0, 0);
            acc[g] = __builtin_amdgcn_mfma_f32_16x16x32_bf16(al, bh, acc[g], 0, 0, 0);
        }
    }
#pragma unroll
    for (int g = 0; g < 3; ++g)
#pragma unroll
        for (int r = 0; r < 4; ++r)
            red[kw][mw][g][(lq * 4 + r) * 16 + lr] = acc[g][r];
    __syncthreads();
    int b = tx >> 4, c = tx & 15;
    int mw2 = b >> 4, ml = b & 15;
    float gz = 0.f, gr_ = 0.f, gc = 0.f;
#pragma unroll
    for (int k2 = 0; k2 < 4; ++k2) {
        gz  += red[k2][mw2][0][ml * 16 + c];
        gr_ += red[k2][mw2][1][ml * 16 + c];
        gc  += red[k2][mw2][2][ml * 16 + c];
    }
    int col = j * 16 + c;
    const float* gx = GX + ((size_t)b * NT + t) * G3 + col;
    float z = sigmoidf_(gx[0]  + gz  + b1[col]);
    float r = sigmoidf_(gx[NU] + gr_ + b1[NU + col]);
    float cc = tanhf(gx[2 * NU] + gc + r * b1[2 * NU + col]);
    float hn = (1.f - z) * cc;
    hdec[(size_t)b * NU + col] = hn;
    size_t row = (size_t)t * NB + b;
    unsigned short hh = f2bf(hn);
    Hs_hi[row * NU + col] = hh;
    Hs_lo[row * NU + col] = f2bf(hn - bf2f(hh));
}

// ---------------------------------------------------------------------------
// Attention (all fp32): block = batch. scores -> softmax -> ctx hi/lo planes.
// ---------------------------------------------------------------------------
__global__ __launch_bounds__(256) void k_attn(const float* __restrict__ hsrc, int hstride,
                                              const float* __restrict__ enc_out,
                                              unsigned short* __restrict__ ctx_hi,
                                              unsigned short* __restrict__ ctx_lo)
{
    __shared__ float h_sh[NU];
    __shared__ float sc_sh[64];
    int tx = threadIdx.x;
    int b = blockIdx.x;
    int wave = tx >> 6, lane = tx & 63;
#pragma unroll
    for (int q = 0; q < 4; ++q)
        h_sh[tx + q * 256] = hsrc[(size_t)b * hstride + tx + q * 256];
    __syncthreads();
    const float* eb = enc_out + (size_t)b * NS * NU;
    for (int s = wave; s < NS; s += 4) {
        const float* es = eb + (size_t)s * NU;
        float p = 0.f;
        for (int k = lane; k < NU; k += 64) p += h_sh[k] * es[k];
        for (int off = 32; off > 0; off >>= 1) p += __shfl_down(p, off);
        if (lane == 0) sc_sh[s] = p;
    }
    __syncthreads();
    if (wave == 0) {
        float v = (lane < NS) ? sc_sh[lane] : -3.0e38f;
        float m = v;
        for (int off = 32; off > 0; off >>= 1) m = fmaxf(m, __shfl_down(m, off));
        m = __shfl(m, 0);
        float e = (lane < NS) ? expf(v - m) : 0.f;
        float ss = e;
        for (int off = 32; off > 0; off >>= 1) ss += __shfl_down(ss, off);
        ss = __shfl(ss, 0);
        if (lane < NS) sc_sh[lane] = e / ss;
    }
    __syncthreads();
#pragma unroll
    for (int q = 0; q < 4; ++q) {
        int k = tx + q * 256;
        float c = 0.f;
#pragma unroll 8
        for (int s = 0; s < NS; ++s) c += sc_sh[s] * eb[(size_t)s * NU + k];
        unsigned short h = f2bf(c);
        ctx_hi[(size_t)b * NU + k] = h;
        ctx_lo[(size_t)b * NU + k] = f2bf(c - bf2f(h));
    }
}

// ---------------------------------------------------------------------------
// FC: grid (10 M-tiles of 256, 128 n-blocks of 64). Wave = 64 rows x 64 cols.
// ---------------------------------------------------------------------------
__global__ __launch_bounds__(256) void k_fc_mfma(const unsigned short* __restrict__ Ah,
                                                 const unsigned short* __restrict__ Al,
                                                 const unsigned short* __restrict__ Bp,
                                                 const float* __restrict__ bias,
                                                 float* __restrict__ out)
{
    int tx = threadIdx.x;
    int w = tx >> 6, l = tx & 63;
    int lq = l >> 4, lr = l & 15;
    int row0 = blockIdx.x * 256 + w * 64;
    int cb = blockIdx.y;
    float4_t acc[4][4];
#pragma unroll
    for (int i = 0; i < 4; ++i)
#pragma unroll
        for (int jn = 0; jn < 4; ++jn) acc[i][jn] = (float4_t){0.f, 0.f, 0.f, 0.f};
#pragma unroll 1
    for (int s = 0; s < NU / 32; ++s) {
        short8_t ah[4], al[4];
#pragma unroll
        for (int mf = 0; mf < 4; ++mf) {
            const unsigned short* ap = Ah + (size_t)(row0 + mf * 16 + lr) * NU + s * 32 + lq * 8;
            const unsigned short* alp = Al + (size_t)(row0 + mf * 16 + lr) * NU + s * 32 + lq * 8;
            ah[mf] = *(const short8_t*)ap;
            al[mf] = *(const short8_t*)alp;
        }
#pragma unroll
        for (int nf = 0; nf < 4; ++nf) {
            const unsigned short* bp = Bp + ((((size_t)cb * 4 + nf) * 32 + s) * 64 + l) * 8;
            short8_t bh = *(const short8_t*)bp;
            short8_t bl = *(const short8_t*)(bp + PO_FC);
#pragma unroll
            for (int mf = 0; mf < 4; ++mf) {
                acc[mf][nf] = __builtin_amdgcn_mfma_f32_16x16x32_bf16(ah[mf], bh, acc[mf][nf], 0, 0, 0);
                acc[mf][nf] = __builtin_amdgcn_mfma_f32_16x16x32_bf16(ah[mf], bl, acc[mf][nf], 0, 0, 0);
                acc[mf][nf] = __builtin_amdgcn_mfma_f32_16x16x32_bf16(al[mf], bh, acc[mf][nf], 0, 0, 0);
            }
        }
    }
#pragma unroll
    for (int nf = 0; nf < 4; ++nf) {
        int v = cb * 64 + nf * 16 + lr;
        float bi = bias[v];
#pragma unroll
        for (int mf = 0; mf < 4; ++mf)
#pragma unroll
            for (int r = 0; r < 4; ++r) {
                int gr = row0 + mf * 16 + lq * 4 + r;   // Hs row = t*64 + b
                if (gr < NT * NB) {
                    int tt = gr >> 6, bb = gr & 63;
                    out[((size_t)bb * NT + tt) * NVO + v] = acc[mf][nf][r] + bi;
                }
            }
    }
}

// ---------------------------------------------------------------------------

extern "C" void kernel_launch(void* const* d_in, const int* in_sizes, int n_in,
                              void* d_out, int out_size, void* d_ws, size_t ws_size,
                              hipStream_t stream)
{
    const int*   inp     = (const int*)d_in[0];
    const int*   targ    = (const int*)d_in[1];
    const float* enc_emb = (const float*)d_in[2];
    const float* enc_Wx  = (const float*)d_in[3];
    const float* enc_Wh  = (const float*)d_in[4];
    const float* enc_b   = (const float*)d_in[5];
    const float* dec_emb = (const float*)d_in[6];
    const float* dec_Wx  = (const float*)d_in[7];
    // d_in[8] = dec_Wh: unused (multiplied by h_zero == 0 in reference)
    const float* dec_b   = (const float*)d_in[9];
    const float* fc_W    = (const float*)d_in[10];
    const float* fc_b    = (const float*)d_in[11];
    float* out = (float*)d_out;

    // ---- workspace carve (bytes) ----
    char* p = (char*)d_ws;
    float*          gx_buf = (float*)p;            // 31.46 MB live during scans
    unsigned short* Bp_fc  = (unsigned short*)p;   // 33.55 MB live after scans
    p += 33554432;
    float* enc_out = (float*)p;                  p += 10485760;  // [b][s][u] fp32
    unsigned short* h_hi0 = (unsigned short*)p;  p += 131072;
    unsigned short* h_lo0 = (unsigned short*)p;  p += 131072;
    unsigned short* h_hi1 = (unsigned short*)p;  p += 131072;
    unsigned short* h_lo1 = (unsigned short*)p;  p += 131072;
    unsigned short* ctx_hi = (unsigned short*)p; p += 131072;
    unsigned short* ctx_lo = (unsigned short*)p; p += 131072;
    float* hdec = (float*)p;                     p += 262144;
    unsigned short* Hs_hi = (unsigned short*)p;  p += 5242880;   // 2560 rows (64 pad)
    unsigned short* Hs_lo = (unsigned short*)p;  p += 5242880;
    unsigned short* Bp_enc = (unsigned short*)p; p += 12582912;
    unsigned short* Bp_dec = (unsigned short*)p; p += 12582912;
    unsigned short* Ax     = (unsigned short*)p; p += 1310720;   // gathered emb bf16
    unsigned short* Bp_gx  = (unsigned short*)p; p += 3145728;   // reused enc->dec

    // zero initial h planes (buffer 0; hi0/lo0 contiguous)
    hipMemsetAsync(h_hi0, 0, 262144, stream);

    // pack recurrent weights
    k_pack_step<<<dim3(64, 96), 64, 0, stream>>>(enc_Wh, Bp_enc);
    k_pack_step<<<dim3(64, 96), 64, 0, stream>>>(dec_Wx, Bp_dec);  // rows 0..1023 (ctx part)

    // ---- encoder x-path (MFMA) ----
    k_pack_b<<<dim3(G3 / 16, NE / 32), 64, 0, stream>>>(enc_Wx, G3, Bp_gx, PO_GX);
    k_gather<<<NB * NS, NE, 0, stream>>>(inp, NS, NS, enc_emb, Ax);
    k_gx_mfma<<<dim3(NB * NS / 64, 48), 256, 0, stream>>>(Ax, Bp_gx, enc_b, gx_buf);

    // ---- encoder scan: one fused kernel per step ----
    for (int t = 0; t < NS; ++t) {
        const unsigned short* rh = (t & 1) ? h_hi1 : h_hi0;
        const unsigned short* rl = (t & 1) ? h_lo1 : h_lo0;
        unsigned short* wh = (t & 1) ? h_hi0 : h_hi1;
        unsigned short* wl = (t & 1) ? h_lo0 : h_lo1;
        k_enc_step<<<64, 1024, 0, stream>>>(rh, rl, Bp_enc, gx_buf, enc_b + G3,
                                            enc_out, wh, wl, t);
    }
    // ctx for decoder t=0 from final encoder hidden
    k_attn<<<64, 256, 0, stream>>>(enc_out + (size_t)(NS - 1) * NU, NS * NU,
                                   enc_out, ctx_hi, ctx_lo);

    // ---- decoder x-path (MFMA) ----
    k_pack_b<<<dim3(G3 / 16, NE / 32), 64, 0, stream>>>(dec_Wx + (size_t)NU * G3, G3, Bp_gx, PO_GX);
    k_gather<<<NB * NT, NE, 0, stream>>>(targ, NS, NT, dec_emb, Ax);
    k_gx_mfma<<<dim3(NB * NT / 64, 48), 256, 0, stream>>>(Ax, Bp_gx, dec_b, gx_buf);

    // ---- decoder scan ----
    for (int t = 0; t < NT; ++t) {
        k_dec_step<<<64, 1024, 0, stream>>>(ctx_hi, ctx_lo, Bp_dec, gx_buf, dec_b + G3,
                                            hdec, Hs_hi, Hs_lo, t);
        if (t < NT - 1)
            k_attn<<<64, 256, 0, stream>>>(hdec, NU, enc_out, ctx_hi, ctx_lo);
    }

    // ---- FC head ----
    k_pack_b<<<dim3(NVO / 16, NU / 32), 64, 0, stream>>>(fc_W, NVO, Bp_fc, PO_FC);
    k_fc_mfma<<<dim3(10, NVO / 64), 256, 0, stream>>>(Hs_hi, Hs_lo, Bp_fc, fc_b, out);
}